// Round 1
// baseline (336.126 us; speedup 1.0000x reference)
//
#include <hip/hip_runtime.h>
#include <math.h>

#define NRULES 1024
#define DM     128
#define ED     256
#define NTOK   8192
#define TCHUNK 16
#define CAP    1024   // max tokens per rule we track; Poisson(8) => counts ~<=30

__global__ __launch_bounds__(256)
void rule_experts_kernel(const float* __restrict__ x,
                         const int*   __restrict__ rules,
                         const float* __restrict__ w1,
                         const float* __restrict__ b1,
                         const float* __restrict__ w2,
                         const float* __restrict__ b2,
                         float*       __restrict__ out)
{
    const int r   = blockIdx.x;    // one block per rule
    const int tid = threadIdx.x;   // 256 threads

    __shared__ int   s_list[CAP];
    __shared__ int   s_cnt;
    __shared__ float s_x[TCHUNK][DM];   // 8 KB
    __shared__ float s_h[TCHUNK][ED];   // 16 KB

    if (tid == 0) s_cnt = 0;
    __syncthreads();

    // Gather this rule's tokens (rules array is 32 KB -> L1/L2 resident).
    for (int t = tid; t < NTOK; t += 256) {
        if (rules[t] == r) {
            int p = atomicAdd(&s_cnt, 1);
            if (p < CAP) s_list[p] = t;
        }
    }
    __syncthreads();
    const int cnt = s_cnt;
    if (cnt == 0) return;

    const float* __restrict__ w1r = w1 + (size_t)r * DM * ED;
    const float* __restrict__ w2r = w2 + (size_t)r * ED * DM;

    // Phase-1 roles: 64 column-groups (4 cols each of E=256) x 4 token-groups (4 tokens each)
    const int cg1 = tid & 63;
    const int tg1 = tid >> 6;
    // Phase-2 roles: 32 column-groups (4 cols each of D=128) x 8 token-groups (2 tokens each)
    const int cg2 = tid & 31;
    const int tg2 = tid >> 5;

    const float4 b1v = *reinterpret_cast<const float4*>(b1 + (size_t)r * ED + cg1 * 4);
    const float4 b2v = *reinterpret_cast<const float4*>(b2 + (size_t)r * DM + cg2 * 4);

    for (int base = 0; base < cnt; base += TCHUNK) {
        const int m = min(TCHUNK, cnt - base);

        // ---- stage x chunk into LDS (zero-fill inactive rows) ----
        for (int i = tid; i < TCHUNK * (DM / 4); i += 256) {
            const int tt = i >> 5;       // DM/4 == 32
            const int c4 = i & 31;
            float4 v = make_float4(0.f, 0.f, 0.f, 0.f);
            if (tt < m)
                v = *reinterpret_cast<const float4*>(
                        x + (size_t)s_list[base + tt] * DM + c4 * 4);
            *reinterpret_cast<float4*>(&s_x[tt][c4 * 4]) = v;
        }
        __syncthreads();

        // ---- phase 1: h[t][e] = sum_d x[t][d] * w1[d][e] ----
        float h[4][4];
        #pragma unroll
        for (int a = 0; a < 4; ++a)
            #pragma unroll
            for (int c = 0; c < 4; ++c) h[a][c] = 0.f;

        #pragma unroll 4
        for (int d = 0; d < DM; ++d) {
            const float4 w = *reinterpret_cast<const float4*>(w1r + (size_t)d * ED + cg1 * 4);
            #pragma unroll
            for (int a = 0; a < 4; ++a) {
                const float xv = s_x[tg1 * 4 + a][d];   // LDS broadcast
                h[a][0] = fmaf(xv, w.x, h[a][0]);
                h[a][1] = fmaf(xv, w.y, h[a][1]);
                h[a][2] = fmaf(xv, w.z, h[a][2]);
                h[a][3] = fmaf(xv, w.w, h[a][3]);
            }
        }

        // ---- bias + exact GELU (erf), park in LDS ----
        const float kInvSqrt2 = 0.70710678118654752440f;
        #pragma unroll
        for (int a = 0; a < 4; ++a) {
            float4 hv;
            hv.x = h[a][0] + b1v.x;
            hv.y = h[a][1] + b1v.y;
            hv.z = h[a][2] + b1v.z;
            hv.w = h[a][3] + b1v.w;
            hv.x = 0.5f * hv.x * (1.f + erff(hv.x * kInvSqrt2));
            hv.y = 0.5f * hv.y * (1.f + erff(hv.y * kInvSqrt2));
            hv.z = 0.5f * hv.z * (1.f + erff(hv.z * kInvSqrt2));
            hv.w = 0.5f * hv.w * (1.f + erff(hv.w * kInvSqrt2));
            *reinterpret_cast<float4*>(&s_h[tg1 * 4 + a][cg1 * 4]) = hv;
        }
        __syncthreads();

        // ---- phase 2: out[t][d] = sum_e h[t][e] * w2[e][d] ----
        float acc[2][4];
        #pragma unroll
        for (int a = 0; a < 2; ++a)
            #pragma unroll
            for (int c = 0; c < 4; ++c) acc[a][c] = 0.f;

        #pragma unroll 4
        for (int e = 0; e < ED; ++e) {
            const float4 w = *reinterpret_cast<const float4*>(w2r + (size_t)e * DM + cg2 * 4);
            #pragma unroll
            for (int a = 0; a < 2; ++a) {
                const float hv = s_h[tg2 * 2 + a][e];   // LDS broadcast per half-wave
                acc[a][0] = fmaf(hv, w.x, acc[a][0]);
                acc[a][1] = fmaf(hv, w.y, acc[a][1]);
                acc[a][2] = fmaf(hv, w.z, acc[a][2]);
                acc[a][3] = fmaf(hv, w.w, acc[a][3]);
            }
        }

        #pragma unroll
        for (int a = 0; a < 2; ++a) {
            const int tt = tg2 * 2 + a;
            if (tt < m) {
                float4 o;
                o.x = acc[a][0] + b2v.x;
                o.y = acc[a][1] + b2v.y;
                o.z = acc[a][2] + b2v.z;
                o.w = acc[a][3] + b2v.w;
                *reinterpret_cast<float4*>(
                    out + (size_t)s_list[base + tt] * DM + cg2 * 4) = o;
            }
        }
        // No trailing barrier needed: next iteration's s_x writes can't race
        // phase-1 readers (they synced at the s_h barrier), and phase-2 only
        // reads s_h/s_list which are not touched until after the next
        // post-stage __syncthreads().
    }
}

extern "C" void kernel_launch(void* const* d_in, const int* in_sizes, int n_in,
                              void* d_out, int out_size, void* d_ws, size_t ws_size,
                              hipStream_t stream) {
    const float* x     = (const float*)d_in[0];
    const int*   rules = (const int*)  d_in[1];
    const float* w1    = (const float*)d_in[2];
    const float* b1    = (const float*)d_in[3];
    const float* w2    = (const float*)d_in[4];
    const float* b2    = (const float*)d_in[5];
    float* out = (float*)d_out;

    (void)in_sizes; (void)n_in; (void)out_size; (void)d_ws; (void)ws_size;

    rule_experts_kernel<<<dim3(NRULES), dim3(256), 0, stream>>>(
        x, rules, w1, b1, w2, b2, out);
}

// Round 6
// 318.963 us; speedup vs baseline: 1.0538x; 1.0538x over previous
//
#include <hip/hip_runtime.h>
#include <math.h>

#define NRULES 1024
#define DM     128
#define ED     256
#define NTOK   8192
#define TCH    16
#define CAP    128   // Poisson(8) token counts; P(cnt>128) ~ 0

__global__ __launch_bounds__(256, 4)
void rule_experts_kernel(const float* __restrict__ x,
                         const int*   __restrict__ rules,
                         const float* __restrict__ w1,
                         const float* __restrict__ b1,
                         const float* __restrict__ w2,
                         const float* __restrict__ b2,
                         float*       __restrict__ out)
{
    const int r   = blockIdx.x;    // one block per rule
    const int tid = threadIdx.x;   // 256 threads

    __shared__ int   s_list[CAP];
    __shared__ int   s_cnt;
    __shared__ float s_x[TCH][DM];   // 8 KB
    __shared__ float s_h[TCH][ED];   // 16 KB
    __shared__ float s_o[TCH][DM];   // 8 KB

    if (tid == 0) s_cnt = 0;
    __syncthreads();

    // Gather this rule's tokens (rules is 32 KB -> L2-resident). int4 scan.
    for (int i = tid; i < NTOK / 4; i += 256) {
        const int4 rv = reinterpret_cast<const int4*>(rules)[i];
        const int t0 = i * 4;
        if (rv.x == r) { int p = atomicAdd(&s_cnt, 1); if (p < CAP) s_list[p] = t0;     }
        if (rv.y == r) { int p = atomicAdd(&s_cnt, 1); if (p < CAP) s_list[p] = t0 + 1; }
        if (rv.z == r) { int p = atomicAdd(&s_cnt, 1); if (p < CAP) s_list[p] = t0 + 2; }
        if (rv.w == r) { int p = atomicAdd(&s_cnt, 1); if (p < CAP) s_list[p] = t0 + 3; }
    }
    __syncthreads();
    const int cnt = min(s_cnt, CAP);
    if (cnt == 0) return;

    // Phase-1 role: thread owns h-column e = tid, FULL d range (no reduction).
    const int e1 = tid;
    const float* __restrict__ w1c = w1 + (size_t)r * DM * ED + e1;   // stride ED per d
    const float b1v = b1[(size_t)r * ED + e1];

    // Phase-2 role: output column d = tid&127, e-half = tid>>7 (2-way reduce).
    const int d2 = tid & 127;
    const int eh = tid >> 7;
    const float* __restrict__ w2c = w2 + (size_t)r * ED * DM + (size_t)(eh * 128) * DM + d2; // stride DM per e
    const float b2v = b2[(size_t)r * DM + d2];

    for (int base = 0; base < cnt; base += TCH) {
        const int m = min(TCH, cnt - base);

        // ---- stage x chunk into LDS (zero-fill padded rows) ----
        for (int i = tid; i < TCH * (DM / 4); i += 256) {
            const int tt = i >> 5;            // DM/4 == 32
            const int c4 = i & 31;
            float4 v = make_float4(0.f, 0.f, 0.f, 0.f);
            if (tt < m)
                v = *reinterpret_cast<const float4*>(
                        x + (size_t)s_list[base + tt] * DM + c4 * 4);
            *reinterpret_cast<float4*>(&s_x[tt][c4 * 4]) = v;
        }
        __syncthreads();

        // ---- phase 1: acc[t] = sum_d x[t][d] * w1[d][e1] ----
        float acc[TCH];
        #pragma unroll
        for (int t = 0; t < TCH; ++t) acc[t] = 0.f;

        for (int d0 = 0; d0 < DM; d0 += 8) {
            float wv[8];
            #pragma unroll
            for (int k = 0; k < 8; ++k) wv[k] = w1c[(size_t)(d0 + k) * ED];  // 8 indep loads in flight
            #pragma unroll
            for (int g = 0; g < 2; ++g) {
                #pragma unroll
                for (int t = 0; t < TCH; ++t) {
                    const float4 xv = *reinterpret_cast<const float4*>(&s_x[t][d0 + g * 4]); // broadcast
                    acc[t] = fmaf(xv.x, wv[g * 4 + 0], acc[t]);
                    acc[t] = fmaf(xv.y, wv[g * 4 + 1], acc[t]);
                    acc[t] = fmaf(xv.z, wv[g * 4 + 2], acc[t]);
                    acc[t] = fmaf(xv.w, wv[g * 4 + 3], acc[t]);
                }
            }
        }

        // ---- bias + exact GELU, park column in LDS ----
        const float kInvSqrt2 = 0.70710678118654752440f;
        #pragma unroll
        for (int t = 0; t < TCH; ++t) {
            float hv = acc[t] + b1v;
            hv = 0.5f * hv * (1.f + erff(hv * kInvSqrt2));
            s_h[t][e1] = hv;   // 2 lanes/bank -> free
        }
        __syncthreads();

        // ---- phase 2: acc2[t] = sum_{e in half} h[t][e] * w2[e][d2] ----
        float acc2[TCH];
        #pragma unroll
        for (int t = 0; t < TCH; ++t) acc2[t] = 0.f;

        for (int e0 = 0; e0 < 128; e0 += 8) {
            float wv[8];
            #pragma unroll
            for (int k = 0; k < 8; ++k) wv[k] = w2c[(size_t)(e0 + k) * DM];  // 8 indep loads
            #pragma unroll
            for (int g = 0; g < 2; ++g) {
                #pragma unroll
                for (int t = 0; t < TCH; ++t) {
                    const float4 hv = *reinterpret_cast<const float4*>(
                        &s_h[t][eh * 128 + e0 + g * 4]);                     // broadcast
                    acc2[t] = fmaf(hv.x, wv[g * 4 + 0], acc2[t]);
                    acc2[t] = fmaf(hv.y, wv[g * 4 + 1], acc2[t]);
                    acc2[t] = fmaf(hv.z, wv[g * 4 + 2], acc2[t]);
                    acc2[t] = fmaf(hv.w, wv[g * 4 + 3], acc2[t]);
                }
            }
        }

        // ---- 2-way reduce across e-halves, bias, store ----
        if (eh == 1) {
            #pragma unroll
            for (int t = 0; t < TCH; ++t) s_o[t][d2] = acc2[t];
        }
        __syncthreads();
        if (eh == 0) {
            #pragma unroll
            for (int t = 0; t < TCH; ++t) {
                if (t < m) {   // m is block-uniform -> no divergence
                    out[(size_t)s_list[base + t] * DM + d2] =
                        acc2[t] + s_o[t][d2] + b2v;
                }
            }
        }
        // No trailing barrier: next-iter s_x writes race nothing (s_x readers
        // finished before the s_h barrier; s_o readers finish before the next
        // stage barrier, s_o writers only write after the next s_h barrier).
    }
}

extern "C" void kernel_launch(void* const* d_in, const int* in_sizes, int n_in,
                              void* d_out, int out_size, void* d_ws, size_t ws_size,
                              hipStream_t stream) {
    const float* x     = (const float*)d_in[0];
    const int*   rules = (const int*)  d_in[1];
    const float* w1    = (const float*)d_in[2];
    const float* b1    = (const float*)d_in[3];
    const float* w2    = (const float*)d_in[4];
    const float* b2    = (const float*)d_in[5];
    float* out = (float*)d_out;

    (void)in_sizes; (void)n_in; (void)out_size; (void)d_ws; (void)ws_size;

    rule_experts_kernel<<<dim3(NRULES), dim3(256), 0, stream>>>(
        x, rules, w1, b1, w2, b2, out);
}